// Round 12
// baseline (201.821 us; speedup 1.0000x reference)
//
#include <hip/hip_runtime.h>

// ---------- types & helpers ----------
typedef unsigned short u16;
typedef float f32x4 __attribute__((ext_vector_type(4)));
typedef short s16x8 __attribute__((ext_vector_type(8)));
typedef unsigned short u16x4 __attribute__((ext_vector_type(4)));

__device__ __forceinline__ u16 f2bf(float f) {
  union { float f; unsigned u; } v; v.f = f;
  unsigned r = v.u + 0x7FFFu + ((v.u >> 16) & 1u);   // RNE
  return (u16)(r >> 16);
}

__device__ __forceinline__ void gload_lds16(const void* g, void* l) {
  __builtin_amdgcn_global_load_lds(
      (const __attribute__((address_space(1))) void*)g,
      (__attribute__((address_space(3))) void*)l, 16, 0, 0);
}

// ---------- fp32 -> bf16 cast ----------
__global__ __launch_bounds__(256) void cast_f32_bf16(
    const float* __restrict__ src, u16* __restrict__ dst, int n4) {
  int i = blockIdx.x * 256 + threadIdx.x;
  if (i >= n4) return;
  f32x4 v = ((const f32x4*)src)[i];
  u16x4 o = { f2bf(v[0]), f2bf(v[1]), f2bf(v[2]), f2bf(v[3]) };
  ((u16x4*)dst)[i] = o;
}

// ---------- pipelined bt-GEMM: C[M,N] = A[M,K] * B[N,K]^T ----------
// BM=128, BN=256, BK=32, 256 threads = 4 waves (2x2), per-wave 64x128.
// Depth-3 LDS pipeline (72 KiB -> 2 blocks/CU), counted vmcnt(6),
// XOR swizzle: slot bits[5:4] ^= linear bits[8:7] (involution, 0-conflict
// verified round 8). FINAL=0: bf16 C, no bias.  FINAL=1: fp32 C + bias[col].
template <int FINAL>
__global__ __launch_bounds__(256, 2) void gemm_pipe(
    const u16* __restrict__ A, const u16* __restrict__ B,
    void* __restrict__ Cout, const float* __restrict__ bias,
    int K, int lda, int ldb, int ldc) {
  __shared__ char smem[3 * 8192 + 3 * 16384];  // A slots [0,24K), B slots [24K,72K)
  const int tid = threadIdx.x;
  const int wid = tid >> 6, lane = tid & 63;
  const int lo = lane & 15, hi = lane >> 4;
  const int wr = wid >> 1, wc = wid & 1;
  const long brow = (long)blockIdx.y * 128;
  const long bcol = (long)blockIdx.x * 256;
  const int T = K >> 5;

  f32x4 acc[4][8] = {};

  const char* Ab = (const char*)(A + (size_t)brow * lda);
  const char* Bb = (const char*)(B + (size_t)bcol * ldb);
  const size_t ldab = (size_t)lda * 2, ldbb = (size_t)ldb * 2;

  const int LA0 = wid * 2048 + lane * 16, LA1 = LA0 + 1024;
  const int LB0 = wid * 4096 + lane * 16, LB1 = LB0 + 1024;
  const int LB2 = LB0 + 2048, LB3 = LB0 + 3072;
#define SRCCOL(L) (((L) & 63) ^ ((((L) >> 7) & 3) << 4))
  const char* aS0 = Ab + (size_t)(LA0 >> 6) * ldab + SRCCOL(LA0);
  const char* aS1 = Ab + (size_t)(LA1 >> 6) * ldab + SRCCOL(LA1);
  const char* bS0 = Bb + (size_t)(LB0 >> 6) * ldbb + SRCCOL(LB0);
  const char* bS1 = Bb + (size_t)(LB1 >> 6) * ldbb + SRCCOL(LB1);
  const char* bS2 = Bb + (size_t)(LB2 >> 6) * ldbb + SRCCOL(LB2);
  const char* bS3 = Bb + (size_t)(LB3 >> 6) * ldbb + SRCCOL(LB3);
#undef SRCCOL

  int ra[4], rb[8];
#pragma unroll
  for (int m = 0; m < 4; ++m) {
    int row = wr * 64 + m * 16 + lo;
    ra[m] = row * 64 + ((hi ^ ((row >> 1) & 3)) << 4);
  }
#pragma unroll
  for (int n = 0; n < 8; ++n) {
    int row = wc * 128 + n * 16 + lo;
    rb[n] = row * 64 + ((hi ^ ((row >> 1) & 3)) << 4);
  }

#define STAGE(t)                                                    \
  {                                                                 \
    char* sa_ = smem + ((t) % 3) * 8192;                            \
    char* sb_ = smem + 24576 + ((t) % 3) * 16384;                   \
    size_t kb_ = (size_t)(t) << 6;                                  \
    gload_lds16(aS0 + kb_, sa_ + LA0);                              \
    gload_lds16(aS1 + kb_, sa_ + LA1);                              \
    gload_lds16(bS0 + kb_, sb_ + LB0);                              \
    gload_lds16(bS1 + kb_, sb_ + LB1);                              \
    gload_lds16(bS2 + kb_, sb_ + LB2);                              \
    gload_lds16(bS3 + kb_, sb_ + LB3);                              \
  }

  STAGE(0); STAGE(1);
  asm volatile("s_waitcnt vmcnt(6)" ::: "memory");
  __builtin_amdgcn_s_barrier();
  __builtin_amdgcn_sched_barrier(0);

  for (int t = 0; t < T; ++t) {
    const char* sa = smem + (t % 3) * 8192;
    const char* sb = smem + 24576 + (t % 3) * 16384;
    s16x8 af[4], bf[8];
#pragma unroll
    for (int m = 0; m < 4; ++m) af[m] = *(const s16x8*)(sa + ra[m]);
#pragma unroll
    for (int n = 0; n < 8; ++n) bf[n] = *(const s16x8*)(sb + rb[n]);
    if (t + 2 < T) STAGE(t + 2);   // slot (t+2)%3 == (t-1)%3: freed by last barrier
    __builtin_amdgcn_s_setprio(1);
#pragma unroll
    for (int m = 0; m < 4; ++m)
#pragma unroll
      for (int n = 0; n < 8; ++n)
        acc[m][n] = __builtin_amdgcn_mfma_f32_16x16x32_bf16(af[m], bf[n], acc[m][n], 0, 0, 0);
    __builtin_amdgcn_s_setprio(0);
    if (t + 2 < T) asm volatile("s_waitcnt vmcnt(6)" ::: "memory");
    else           asm volatile("s_waitcnt vmcnt(0)" ::: "memory");
    __builtin_amdgcn_s_barrier();
    __builtin_amdgcn_sched_barrier(0);
  }
#undef STAGE

#pragma unroll
  for (int m = 0; m < 4; ++m) {
#pragma unroll
    for (int n = 0; n < 8; ++n) {
#pragma unroll
      for (int r = 0; r < 4; ++r) {
        size_t row = brow + wr * 64 + m * 16 + hi * 4 + r;
        size_t col = bcol + wc * 128 + n * 16 + lo;
        float v = acc[m][n][r];
        if (FINAL) ((float*)Cout)[row * ldc + col] = v + bias[col];
        else       ((u16*)Cout)[row * ldc + col] = f2bf(v);
      }
    }
  }
}

// ---------- Ke/Vf partial: per (kc, bh, type*4+ns) block: 64k x 64d over 1024 n ----
// 64-n steps, depth-3 register rotation, W direct-to-A-frag, QKV transposed
// via double-buffered LDS.
// ROUND-11 FIX: __syncthreads() drains vmcnt(0) (hipcc semantics), killing
// the register prefetch. Use lgkmcnt(0)+raw s_barrier so the t+3 global
// loads stay in flight across the barrier (compiler guards their reads).
__global__ __launch_bounds__(256) void kevf_kernel(
    const float* __restrict__ We, const float* __restrict__ Wf,
    const u16* __restrict__ QKV, float* __restrict__ part) {
  __shared__ u16 Vt[2][64 * 64];   // [buf][dd*64 + swizzled n], 2 x 8KB
  const int type = blockIdx.z >> 2, ns = blockIdx.z & 3;
  const int bh = blockIdx.y, b = bh >> 4, h = bh & 15;
  const int kk0 = blockIdx.x * 64;
  const float* W = (type ? Wf : We) + ((size_t)(h * 256 + kk0)) * 4096;
  const int col0 = (type ? 2048 : 1024) + h * 64;
  const int tid = threadIdx.x, wid = tid >> 6, lane = tid & 63;
  const int lo = lane & 15, hi = lane >> 4;
  const int nbeg = ns << 10;

  const int rr = wid * 16 + lo;
  const float* wsrc = W + (size_t)rr * 4096 + nbeg + hi * 8;
  const int qn = tid >> 2, qc = (tid & 3) * 16;
  const u16* qsrc = QKV + ((size_t)b * 4096 + nbeg + qn) * 3072 + col0 + qc;

  f32x4 acc[4] = {};
  f32x4 w[3][4];
  s16x8 q[3][2];

#define KISSUE(t) {                                       \
    const float* wp_ = wsrc + (size_t)(t) * 64;           \
    w[(t) % 3][0] = *(const f32x4*)wp_;                   \
    w[(t) % 3][1] = *(const f32x4*)(wp_ + 4);             \
    w[(t) % 3][2] = *(const f32x4*)(wp_ + 32);            \
    w[(t) % 3][3] = *(const f32x4*)(wp_ + 36);            \
    const u16* qp_ = qsrc + (size_t)(t) * 64 * 3072;      \
    q[(t) % 3][0] = *(const s16x8*)qp_;                   \
    q[(t) % 3][1] = *(const s16x8*)(qp_ + 8); }

  KISSUE(0); KISSUE(1); KISSUE(2);
#pragma unroll
  for (int t = 0; t < 16; ++t) {
    u16* vb = Vt[t & 1];
    // transpose-stage QKV rows -> Vt[dd][n]  (consumes q[t%3])
#pragma unroll
    for (int e = 0; e < 16; ++e) {
      int dd = qc + e;
      int sw = (dd & 7) ^ ((dd >> 4) & 3);
      u16 val = (e < 8) ? (u16)q[t % 3][0][e] : (u16)q[t % 3][1][e - 8];
      vb[dd * 64 + (qn ^ (sw << 3))] = val;
    }
    // A-frags from registers (fp32 -> bf16) — consumes w[t%3] BEFORE re-issue
    s16x8 a0, a1;
#pragma unroll
    for (int j = 0; j < 4; ++j) {
      a0[j]     = (short)f2bf(w[t % 3][0][j]);
      a0[j + 4] = (short)f2bf(w[t % 3][1][j]);
      a1[j]     = (short)f2bf(w[t % 3][2][j]);
      a1[j + 4] = (short)f2bf(w[t % 3][3][j]);
    }
    if (t + 3 < 16) KISSUE(t + 3);   // rotation slot (t+3)%3 == t%3: now free
    // LDS-write visibility only; do NOT drain vmcnt (keep prefetch in flight)
    asm volatile("s_waitcnt lgkmcnt(0)" ::: "memory");
    __builtin_amdgcn_s_barrier();
    __builtin_amdgcn_sched_barrier(0);
#pragma unroll
    for (int dt = 0; dt < 4; ++dt) {
      int dd = dt * 16 + lo;
      int sw = (lo & 7) ^ dt;
      s16x8 b0 = *(const s16x8*)&vb[dd * 64 + ((hi * 8) ^ (sw << 3))];
      s16x8 b1 = *(const s16x8*)&vb[dd * 64 + ((32 + hi * 8) ^ (sw << 3))];
      acc[dt] = __builtin_amdgcn_mfma_f32_16x16x32_bf16(a0, b0, acc[dt], 0, 0, 0);
      acc[dt] = __builtin_amdgcn_mfma_f32_16x16x32_bf16(a1, b1, acc[dt], 0, 0, 0);
    }
    // WAR-safe: this wave's step-t ds_reads drain at its step-t+1 lgkmcnt(0);
    // all waves pass barrier(t+1) before any wave rewrites Vt[t&1] at t+2.
  }
#undef KISSUE

  const size_t pbase = ((size_t)((type * 32 + bh) * 4 + blockIdx.x) * 4 + ns) * 4096;
#pragma unroll
  for (int dt = 0; dt < 4; ++dt)
#pragma unroll
    for (int rg = 0; rg < 4; ++rg) {
      int kkl = wid * 16 + hi * 4 + rg;
      int dd = dt * 16 + lo;
      part[pbase + kkl * 64 + dd] = acc[dt][rg];
    }
}

// ---------- reduce 4 n-splits, add bias, write KeT (type0) / Vf (type1) ----------
__global__ __launch_bounds__(256) void kevf_reduce(
    const float* __restrict__ part, const float* __restrict__ bE,
    const float* __restrict__ bF, u16* __restrict__ KeT, u16* __restrict__ Vf) {
  const int tb = blockIdx.x;
  const int type = tb >> 7, bh = (tb >> 2) & 31, kc = tb & 3;
  const int t = threadIdx.x;
  const int kkl = t >> 2, dd0 = (t & 3) * 16;
  const float* p = part + (size_t)tb * 16384 + kkl * 64 + dd0;
  f32x4 s[4];
#pragma unroll
  for (int j = 0; j < 4; ++j) s[j] = ((const f32x4*)p)[j];
#pragma unroll
  for (int ns = 1; ns < 4; ++ns)
#pragma unroll
    for (int j = 0; j < 4; ++j) {
      f32x4 v = ((const f32x4*)(p + ns * 4096))[j];
      s[j][0] += v[0]; s[j][1] += v[1]; s[j][2] += v[2]; s[j][3] += v[3];
    }
  const int kk = kc * 64 + kkl;
  const float bias = (type ? bF : bE)[(bh & 15) * 256 + kk];
  if (type == 0) {
    u16* o = KeT + ((size_t)bh * 256 + kk) * 64 + dd0;
#pragma unroll
    for (int j = 0; j < 4; ++j) {
      u16x4 w = { f2bf(s[j][0] + bias), f2bf(s[j][1] + bias),
                  f2bf(s[j][2] + bias), f2bf(s[j][3] + bias) };
      *(u16x4*)(o + j * 4) = w;
    }
  } else {
#pragma unroll
    for (int j = 0; j < 4; ++j)
#pragma unroll
      for (int e = 0; e < 4; ++e) {
        int dd = dd0 + j * 4 + e;
        Vf[((size_t)bh * 64 + dd) * 256 + kk] = f2bf(s[j][e] + bias);
      }
  }
}

// ---------- fused attention: scores -> softmax -> PV -> gelu ----------
__global__ __launch_bounds__(256) void attn_fused(
    const u16* __restrict__ QKV, const u16* __restrict__ KeT,
    const u16* __restrict__ Vf, u16* __restrict__ attn) {
  __shared__ char smem[65536];
  char* sKe = smem;           // [256][128B] swizzled (aliased by P later)
  char* sVf = smem + 32768;   // [64][512B] swizzled
  const int tid = threadIdx.x, wid = tid >> 6, lane = tid & 63;
  const int lo = lane & 15, hi = lane >> 4;
  const int bh = blockIdx.y, b = bh >> 4, h = bh & 15;
  const int n0 = blockIdx.x * 64;

  const char* keg = (const char*)(KeT + (size_t)bh * 256 * 64);
  const char* vfg = (const char*)(Vf + (size_t)bh * 64 * 256);
#pragma unroll
  for (int i = 0; i < 8; ++i) {
    int ob = wid * 8192 + i * 1024;
    int o = ob + lane * 16;
    int kr = o >> 7, kc = o & 127;
    gload_lds16(keg + kr * 128 + (kc ^ ((kr & 7) << 4)), sKe + ob);
    int vr = o >> 9, vc = o & 511;
    gload_lds16(vfg + vr * 512 + (vc ^ ((vr & 7) << 4)), sVf + ob);
  }
  const u16* qp = QKV + (size_t)(b * 4096 + n0 + wid * 16 + lo) * 3072 + h * 64;
  s16x8 qf0 = *(const s16x8*)(qp + hi * 8);
  s16x8 qf1 = *(const s16x8*)(qp + 32 + hi * 8);
  __syncthreads();

  f32x4 sc[16];
#pragma unroll
  for (int nt = 0; nt < 16; ++nt) {
    int kk = nt * 16 + lo;
    int sw = (kk & 7) << 4;
    s16x8 b0 = *(const s16x8*)(sKe + kk * 128 + ((hi * 16) ^ sw));
    s16x8 b1 = *(const s16x8*)(sKe + kk * 128 + ((64 + hi * 16) ^ sw));
    f32x4 c = {0.f, 0.f, 0.f, 0.f};
    c = __builtin_amdgcn_mfma_f32_16x16x32_bf16(qf0, b0, c, 0, 0, 0);
    c = __builtin_amdgcn_mfma_f32_16x16x32_bf16(qf1, b1, c, 0, 0, 0);
    sc[nt] = c;
  }
  float mx[4], inv[4];
#pragma unroll
  for (int r = 0; r < 4; ++r) {
    float m = sc[0][r];
#pragma unroll
    for (int nt = 1; nt < 16; ++nt) m = fmaxf(m, sc[nt][r]);
    m = fmaxf(m, __shfl_xor(m, 1));
    m = fmaxf(m, __shfl_xor(m, 2));
    m = fmaxf(m, __shfl_xor(m, 4));
    m = fmaxf(m, __shfl_xor(m, 8));
    mx[r] = m;
  }
  const float SCL = 0.125f * 1.4426950408889634f;   // (1/sqrt(64)) * log2(e)
  float sm[4] = {0.f, 0.f, 0.f, 0.f};
#pragma unroll
  for (int nt = 0; nt < 16; ++nt)
#pragma unroll
    for (int r = 0; r < 4; ++r) {
      float p = exp2f((sc[nt][r] - mx[r]) * SCL);
      sc[nt][r] = p;
      sm[r] += p;
    }
#pragma unroll
  for (int r = 0; r < 4; ++r) {
    float s = sm[r];
    s += __shfl_xor(s, 1);
    s += __shfl_xor(s, 2);
    s += __shfl_xor(s, 4);
    s += __shfl_xor(s, 8);
    inv[r] = 1.0f / s;
  }
  __syncthreads();            // all waves done reading sKe
  char* pb = smem + wid * 8192;  // P aliases sKe region: [16 rows][512B] per wave
#pragma unroll
  for (int nt = 0; nt < 16; ++nt)
#pragma unroll
    for (int r = 0; r < 4; ++r) {
      int row = hi * 4 + r;
      int kk = nt * 16 + lo;
      *(u16*)(pb + row * 512 + ((kk * 2) ^ ((row & 7) << 4))) = f2bf(sc[nt][r] * inv[r]);
    }
  __syncthreads();
  s16x8 pa[8];
#pragma unroll
  for (int ks = 0; ks < 8; ++ks)
    pa[ks] = *(const s16x8*)(pb + lo * 512 + ((ks * 64 + hi * 16) ^ ((lo & 7) << 4)));
#pragma unroll
  for (int dt = 0; dt < 4; ++dt) {
    int dd = dt * 16 + lo;
    int sw = (dd & 7) << 4;
    f32x4 o = {0.f, 0.f, 0.f, 0.f};
#pragma unroll
    for (int ks = 0; ks < 8; ++ks) {
      s16x8 vb = *(const s16x8*)(sVf + dd * 512 + ((ks * 64 + hi * 16) ^ sw));
      o = __builtin_amdgcn_mfma_f32_16x16x32_bf16(pa[ks], vb, o, 0, 0, 0);
    }
#pragma unroll
    for (int r = 0; r < 4; ++r) {
      int row = n0 + wid * 16 + hi * 4 + r;
      float x = o[r];
      float g = 0.5f * x * (1.0f + erff(x * 0.7071067811865476f));
      attn[(size_t)(b * 4096 + row) * 1024 + h * 64 + dd] = f2bf(g);
    }
  }
}

// ---------- launcher ----------
extern "C" void kernel_launch(void* const* d_in, const int* in_sizes, int n_in,
                              void* d_out, int out_size, void* d_ws, size_t ws_size,
                              hipStream_t stream) {
  const float* x  = (const float*)d_in[0];
  const float* Wq = (const float*)d_in[1];
  const float* Wk = (const float*)d_in[2];
  const float* Wv = (const float*)d_in[3];
  const float* We = (const float*)d_in[4];
  const float* bE = (const float*)d_in[5];
  const float* Wf = (const float*)d_in[6];
  const float* bF = (const float*)d_in[7];
  const float* Wo = (const float*)d_in[8];
  const float* bo = (const float*)d_in[9];
  float* out = (float*)d_out;

  char* ws = (char*)d_ws;
  u16* xb   = (u16*)(ws);                 // 16,777,216 B  [8192][1024] bf16
  u16* Wqkv = (u16*)(ws + 16777216);      //  6,291,456 B  [3072][1024] bf16
  u16* Wob  = (u16*)(ws + 23068672);      //  2,097,152 B  [1024][1024] bf16
  u16* QKV  = (u16*)(ws + 25165824);      // 50,331,648 B  [8192][3072] bf16
  u16* KeT  = (u16*)(ws + 75497472);      //  1,048,576 B  [32][256][64] bf16
  u16* Vf   = (u16*)(ws + 76546048);      //  1,048,576 B  [32][64][256] bf16
  u16* attn = (u16*)(ws + 77594624);      // 16,777,216 B  [8192][1024] bf16
  float* part = (float*)(ws);             // 16,777,216 B  aliases xb (dead after QKV GEMM)

  cast_f32_bf16<<<8192, 256, 0, stream>>>(x, xb, 2097152);
  cast_f32_bf16<<<1024, 256, 0, stream>>>(Wq, Wqkv, 262144);
  cast_f32_bf16<<<1024, 256, 0, stream>>>(Wk, Wqkv + 1048576, 262144);
  cast_f32_bf16<<<1024, 256, 0, stream>>>(Wv, Wqkv + 2097152, 262144);
  cast_f32_bf16<<<1024, 256, 0, stream>>>(Wo, Wob, 262144);

  // QKV projection: [8192,3072] = x[8192,1024] @ Wqkv[3072,1024]^T
  gemm_pipe<0><<<dim3(12, 64), 256, 0, stream>>>(xb, Wqkv, QKV, nullptr,
                                                 1024, 1024, 1024, 3072);
  // Ke/Vf low-rank projections: 4-way n-split partials + reduce
  kevf_kernel<<<dim3(4, 32, 8), 256, 0, stream>>>(We, Wf, QKV, part);
  kevf_reduce<<<256, 256, 0, stream>>>(part, bE, bF, KeT, Vf);
  // fused scores/softmax/PV/gelu
  attn_fused<<<dim3(64, 32), 256, 0, stream>>>(QKV, KeT, Vf, attn);
  // output projection + bias
  gemm_pipe<1><<<dim3(4, 64), 256, 0, stream>>>(attn, Wob, out, bo,
                                                1024, 1024, 1024, 1024);
}

// Round 13
// 200.960 us; speedup vs baseline: 1.0043x; 1.0043x over previous
//
#include <hip/hip_runtime.h>

// ---------- types & helpers ----------
typedef unsigned short u16;
typedef float f32x4 __attribute__((ext_vector_type(4)));
typedef short s16x8 __attribute__((ext_vector_type(8)));
typedef unsigned short u16x4 __attribute__((ext_vector_type(4)));

__device__ __forceinline__ u16 f2bf(float f) {
  union { float f; unsigned u; } v; v.f = f;
  unsigned r = v.u + 0x7FFFu + ((v.u >> 16) & 1u);   // RNE
  return (u16)(r >> 16);
}

__device__ __forceinline__ void gload_lds16(const void* g, void* l) {
  __builtin_amdgcn_global_load_lds(
      (const __attribute__((address_space(1))) void*)g,
      (__attribute__((address_space(3))) void*)l, 16, 0, 0);
}

// ---------- fp32 -> bf16 cast ----------
__global__ __launch_bounds__(256) void cast_f32_bf16(
    const float* __restrict__ src, u16* __restrict__ dst, int n4) {
  int i = blockIdx.x * 256 + threadIdx.x;
  if (i >= n4) return;
  f32x4 v = ((const f32x4*)src)[i];
  u16x4 o = { f2bf(v[0]), f2bf(v[1]), f2bf(v[2]), f2bf(v[3]) };
  ((u16x4*)dst)[i] = o;
}

// ---------- pipelined bt-GEMM: C[M,N] = A[M,K] * B[N,K]^T ----------
// BM=128, BN=256, BK=32, 256 threads = 4 waves (2x2), per-wave 64x128.
// Depth-3 LDS pipeline (72 KiB -> 2 blocks/CU), counted vmcnt(6),
// XOR swizzle: slot bits[5:4] ^= linear bits[8:7] (involution, 0-conflict
// verified round 8). FINAL=0: bf16 C, no bias.  FINAL=1: fp32 C + bias[col].
template <int FINAL>
__global__ __launch_bounds__(256, 2) void gemm_pipe(
    const u16* __restrict__ A, const u16* __restrict__ B,
    void* __restrict__ Cout, const float* __restrict__ bias,
    int K, int lda, int ldb, int ldc) {
  __shared__ char smem[3 * 8192 + 3 * 16384];  // A slots [0,24K), B slots [24K,72K)
  const int tid = threadIdx.x;
  const int wid = tid >> 6, lane = tid & 63;
  const int lo = lane & 15, hi = lane >> 4;
  const int wr = wid >> 1, wc = wid & 1;
  const long brow = (long)blockIdx.y * 128;
  const long bcol = (long)blockIdx.x * 256;
  const int T = K >> 5;

  f32x4 acc[4][8] = {};

  const char* Ab = (const char*)(A + (size_t)brow * lda);
  const char* Bb = (const char*)(B + (size_t)bcol * ldb);
  const size_t ldab = (size_t)lda * 2, ldbb = (size_t)ldb * 2;

  const int LA0 = wid * 2048 + lane * 16, LA1 = LA0 + 1024;
  const int LB0 = wid * 4096 + lane * 16, LB1 = LB0 + 1024;
  const int LB2 = LB0 + 2048, LB3 = LB0 + 3072;
#define SRCCOL(L) (((L) & 63) ^ ((((L) >> 7) & 3) << 4))
  const char* aS0 = Ab + (size_t)(LA0 >> 6) * ldab + SRCCOL(LA0);
  const char* aS1 = Ab + (size_t)(LA1 >> 6) * ldab + SRCCOL(LA1);
  const char* bS0 = Bb + (size_t)(LB0 >> 6) * ldbb + SRCCOL(LB0);
  const char* bS1 = Bb + (size_t)(LB1 >> 6) * ldbb + SRCCOL(LB1);
  const char* bS2 = Bb + (size_t)(LB2 >> 6) * ldbb + SRCCOL(LB2);
  const char* bS3 = Bb + (size_t)(LB3 >> 6) * ldbb + SRCCOL(LB3);
#undef SRCCOL

  int ra[4], rb[8];
#pragma unroll
  for (int m = 0; m < 4; ++m) {
    int row = wr * 64 + m * 16 + lo;
    ra[m] = row * 64 + ((hi ^ ((row >> 1) & 3)) << 4);
  }
#pragma unroll
  for (int n = 0; n < 8; ++n) {
    int row = wc * 128 + n * 16 + lo;
    rb[n] = row * 64 + ((hi ^ ((row >> 1) & 3)) << 4);
  }

#define STAGE(t)                                                    \
  {                                                                 \
    char* sa_ = smem + ((t) % 3) * 8192;                            \
    char* sb_ = smem + 24576 + ((t) % 3) * 16384;                   \
    size_t kb_ = (size_t)(t) << 6;                                  \
    gload_lds16(aS0 + kb_, sa_ + LA0);                              \
    gload_lds16(aS1 + kb_, sa_ + LA1);                              \
    gload_lds16(bS0 + kb_, sb_ + LB0);                              \
    gload_lds16(bS1 + kb_, sb_ + LB1);                              \
    gload_lds16(bS2 + kb_, sb_ + LB2);                              \
    gload_lds16(bS3 + kb_, sb_ + LB3);                              \
  }

  STAGE(0); STAGE(1);
  asm volatile("s_waitcnt vmcnt(6)" ::: "memory");
  __builtin_amdgcn_s_barrier();
  __builtin_amdgcn_sched_barrier(0);

  for (int t = 0; t < T; ++t) {
    const char* sa = smem + (t % 3) * 8192;
    const char* sb = smem + 24576 + (t % 3) * 16384;
    s16x8 af[4], bf[8];
#pragma unroll
    for (int m = 0; m < 4; ++m) af[m] = *(const s16x8*)(sa + ra[m]);
#pragma unroll
    for (int n = 0; n < 8; ++n) bf[n] = *(const s16x8*)(sb + rb[n]);
    if (t + 2 < T) STAGE(t + 2);   // slot (t+2)%3 == (t-1)%3: freed by last barrier
    __builtin_amdgcn_s_setprio(1);
#pragma unroll
    for (int m = 0; m < 4; ++m)
#pragma unroll
      for (int n = 0; n < 8; ++n)
        acc[m][n] = __builtin_amdgcn_mfma_f32_16x16x32_bf16(af[m], bf[n], acc[m][n], 0, 0, 0);
    __builtin_amdgcn_s_setprio(0);
    if (t + 2 < T) asm volatile("s_waitcnt vmcnt(6)" ::: "memory");
    else           asm volatile("s_waitcnt vmcnt(0)" ::: "memory");
    __builtin_amdgcn_s_barrier();
    __builtin_amdgcn_sched_barrier(0);
  }
#undef STAGE

#pragma unroll
  for (int m = 0; m < 4; ++m) {
#pragma unroll
    for (int n = 0; n < 8; ++n) {
#pragma unroll
      for (int r = 0; r < 4; ++r) {
        size_t row = brow + wr * 64 + m * 16 + hi * 4 + r;
        size_t col = bcol + wc * 128 + n * 16 + lo;
        float v = acc[m][n][r];
        if (FINAL) ((float*)Cout)[row * ldc + col] = v + bias[col];
        else       ((u16*)Cout)[row * ldc + col] = f2bf(v);
      }
    }
  }
}

// ---------- Ke/Vf partial: per (kc, bh, type*4+ns) block: 64k x 64d over 1024 n ----
// ROUND-12 DIAGNOSIS: rotation ARRAYS w[3][4]/q[3][2] were allocated in
// SCRATCH (VGPR_Count 80 < 88 required) -> every prefetch was a device-mem
// round trip -> 70 us invariant. Fix: fully NAMED register sets (A,B,C),
// 16 explicitly unrolled steps, raw s_barrier + lgkmcnt-only (vmcnt stays
// counted by the compiler's per-use waits).
__global__ __launch_bounds__(256) void kevf_kernel(
    const float* __restrict__ We, const float* __restrict__ Wf,
    const u16* __restrict__ QKV, float* __restrict__ part) {
  __shared__ u16 Vt[2][64 * 64];   // [buf][dd*64 + swizzled n], 2 x 8KB
  const int type = blockIdx.z >> 2, ns = blockIdx.z & 3;
  const int bh = blockIdx.y, b = bh >> 4, h = bh & 15;
  const int kk0 = blockIdx.x * 64;
  const float* W = (type ? Wf : We) + ((size_t)(h * 256 + kk0)) * 4096;
  const int col0 = (type ? 2048 : 1024) + h * 64;
  const int tid = threadIdx.x, wid = tid >> 6, lane = tid & 63;
  const int lo = lane & 15, hi = lane >> 4;
  const int nbeg = ns << 10;

  const int rr = wid * 16 + lo;
  const float* wsrc = W + (size_t)rr * 4096 + nbeg + hi * 8;
  const int qn = tid >> 2, qc = (tid & 3) * 16;
  const u16* qsrc = QKV + ((size_t)b * 4096 + nbeg + qn) * 3072 + col0 + qc;

  f32x4 acc[4] = {};
  // three NAMED prefetch sets (depth-3 rotation, zero dynamic indexing)
  f32x4 Aw0, Aw1, Aw2, Aw3, Bw0, Bw1, Bw2, Bw3, Cw0, Cw1, Cw2, Cw3;
  s16x8 Aq0, Aq1, Bq0, Bq1, Cq0, Cq1;

#define KISSUE(S, t) {                                    \
    const float* wp_ = wsrc + (size_t)(t) * 64;           \
    S##w0 = *(const f32x4*)wp_;                           \
    S##w1 = *(const f32x4*)(wp_ + 4);                     \
    S##w2 = *(const f32x4*)(wp_ + 32);                    \
    S##w3 = *(const f32x4*)(wp_ + 36);                    \
    const u16* qp_ = qsrc + (size_t)(t) * 64 * 3072;      \
    S##q0 = *(const s16x8*)qp_;                           \
    S##q1 = *(const s16x8*)(qp_ + 8); }

#define KSTEP(S, t) {                                                    \
    u16* vb_ = Vt[(t) & 1];                                              \
    _Pragma("unroll")                                                    \
    for (int e = 0; e < 16; ++e) {                                       \
      int dd = qc + e;                                                   \
      int sw = (dd & 7) ^ ((dd >> 4) & 3);                               \
      u16 val = (e < 8) ? (u16)S##q0[e] : (u16)S##q1[e - 8];             \
      vb_[dd * 64 + (qn ^ (sw << 3))] = val;                             \
    }                                                                    \
    s16x8 a0_, a1_;                                                      \
    _Pragma("unroll")                                                    \
    for (int j = 0; j < 4; ++j) {                                        \
      a0_[j]     = (short)f2bf(S##w0[j]);                                \
      a0_[j + 4] = (short)f2bf(S##w1[j]);                                \
      a1_[j]     = (short)f2bf(S##w2[j]);                                \
      a1_[j + 4] = (short)f2bf(S##w3[j]);                                \
    }                                                                    \
    if ((t) + 3 < 16) KISSUE(S, (t) + 3);                                \
    asm volatile("s_waitcnt lgkmcnt(0)" ::: "memory");                   \
    __builtin_amdgcn_s_barrier();                                        \
    __builtin_amdgcn_sched_barrier(0);                                   \
    _Pragma("unroll")                                                    \
    for (int dt = 0; dt < 4; ++dt) {                                     \
      int dd = dt * 16 + lo;                                             \
      int sw = (lo & 7) ^ dt;                                            \
      s16x8 b0_ = *(const s16x8*)&vb_[dd * 64 + ((hi * 8) ^ (sw << 3))]; \
      s16x8 b1_ = *(const s16x8*)&vb_[dd * 64 + ((32 + hi * 8) ^ (sw << 3))]; \
      acc[dt] = __builtin_amdgcn_mfma_f32_16x16x32_bf16(a0_, b0_, acc[dt], 0, 0, 0); \
      acc[dt] = __builtin_amdgcn_mfma_f32_16x16x32_bf16(a1_, b1_, acc[dt], 0, 0, 0); \
    } }

  KISSUE(A, 0); KISSUE(B, 1); KISSUE(C, 2);
  KSTEP(A, 0);  KSTEP(B, 1);  KSTEP(C, 2);
  KSTEP(A, 3);  KSTEP(B, 4);  KSTEP(C, 5);
  KSTEP(A, 6);  KSTEP(B, 7);  KSTEP(C, 8);
  KSTEP(A, 9);  KSTEP(B, 10); KSTEP(C, 11);
  KSTEP(A, 12); KSTEP(B, 13); KSTEP(C, 14);
  KSTEP(A, 15);
#undef KISSUE
#undef KSTEP

  const size_t pbase = ((size_t)((type * 32 + bh) * 4 + blockIdx.x) * 4 + ns) * 4096;
#pragma unroll
  for (int dt = 0; dt < 4; ++dt)
#pragma unroll
    for (int rg = 0; rg < 4; ++rg) {
      int kkl = wid * 16 + hi * 4 + rg;
      int dd = dt * 16 + lo;
      part[pbase + kkl * 64 + dd] = acc[dt][rg];
    }
}

// ---------- reduce 4 n-splits, add bias, write KeT (type0) / Vf (type1) ----------
__global__ __launch_bounds__(256) void kevf_reduce(
    const float* __restrict__ part, const float* __restrict__ bE,
    const float* __restrict__ bF, u16* __restrict__ KeT, u16* __restrict__ Vf) {
  const int tb = blockIdx.x;
  const int type = tb >> 7, bh = (tb >> 2) & 31, kc = tb & 3;
  const int t = threadIdx.x;
  const int kkl = t >> 2, dd0 = (t & 3) * 16;
  const float* p = part + (size_t)tb * 16384 + kkl * 64 + dd0;
  f32x4 s[4];
#pragma unroll
  for (int j = 0; j < 4; ++j) s[j] = ((const f32x4*)p)[j];
#pragma unroll
  for (int ns = 1; ns < 4; ++ns)
#pragma unroll
    for (int j = 0; j < 4; ++j) {
      f32x4 v = ((const f32x4*)(p + ns * 4096))[j];
      s[j][0] += v[0]; s[j][1] += v[1]; s[j][2] += v[2]; s[j][3] += v[3];
    }
  const int kk = kc * 64 + kkl;
  const float bias = (type ? bF : bE)[(bh & 15) * 256 + kk];
  if (type == 0) {
    u16* o = KeT + ((size_t)bh * 256 + kk) * 64 + dd0;
#pragma unroll
    for (int j = 0; j < 4; ++j) {
      u16x4 w = { f2bf(s[j][0] + bias), f2bf(s[j][1] + bias),
                  f2bf(s[j][2] + bias), f2bf(s[j][3] + bias) };
      *(u16x4*)(o + j * 4) = w;
    }
  } else {
#pragma unroll
    for (int j = 0; j < 4; ++j)
#pragma unroll
      for (int e = 0; e < 4; ++e) {
        int dd = dd0 + j * 4 + e;
        Vf[((size_t)bh * 64 + dd) * 256 + kk] = f2bf(s[j][e] + bias);
      }
  }
}

// ---------- fused attention: scores -> softmax -> PV -> gelu ----------
__global__ __launch_bounds__(256) void attn_fused(
    const u16* __restrict__ QKV, const u16* __restrict__ KeT,
    const u16* __restrict__ Vf, u16* __restrict__ attn) {
  __shared__ char smem[65536];
  char* sKe = smem;           // [256][128B] swizzled (aliased by P later)
  char* sVf = smem + 32768;   // [64][512B] swizzled
  const int tid = threadIdx.x, wid = tid >> 6, lane = tid & 63;
  const int lo = lane & 15, hi = lane >> 4;
  const int bh = blockIdx.y, b = bh >> 4, h = bh & 15;
  const int n0 = blockIdx.x * 64;

  const char* keg = (const char*)(KeT + (size_t)bh * 256 * 64);
  const char* vfg = (const char*)(Vf + (size_t)bh * 64 * 256);
#pragma unroll
  for (int i = 0; i < 8; ++i) {
    int ob = wid * 8192 + i * 1024;
    int o = ob + lane * 16;
    int kr = o >> 7, kc = o & 127;
    gload_lds16(keg + kr * 128 + (kc ^ ((kr & 7) << 4)), sKe + ob);
    int vr = o >> 9, vc = o & 511;
    gload_lds16(vfg + vr * 512 + (vc ^ ((vr & 7) << 4)), sVf + ob);
  }
  const u16* qp = QKV + (size_t)(b * 4096 + n0 + wid * 16 + lo) * 3072 + h * 64;
  s16x8 qf0 = *(const s16x8*)(qp + hi * 8);
  s16x8 qf1 = *(const s16x8*)(qp + 32 + hi * 8);
  __syncthreads();

  f32x4 sc[16];
#pragma unroll
  for (int nt = 0; nt < 16; ++nt) {
    int kk = nt * 16 + lo;
    int sw = (kk & 7) << 4;
    s16x8 b0 = *(const s16x8*)(sKe + kk * 128 + ((hi * 16) ^ sw));
    s16x8 b1 = *(const s16x8*)(sKe + kk * 128 + ((64 + hi * 16) ^ sw));
    f32x4 c = {0.f, 0.f, 0.f, 0.f};
    c = __builtin_amdgcn_mfma_f32_16x16x32_bf16(qf0, b0, c, 0, 0, 0);
    c = __builtin_amdgcn_mfma_f32_16x16x32_bf16(qf1, b1, c, 0, 0, 0);
    sc[nt] = c;
  }
  float mx[4], inv[4];
#pragma unroll
  for (int r = 0; r < 4; ++r) {
    float m = sc[0][r];
#pragma unroll
    for (int nt = 1; nt < 16; ++nt) m = fmaxf(m, sc[nt][r]);
    m = fmaxf(m, __shfl_xor(m, 1));
    m = fmaxf(m, __shfl_xor(m, 2));
    m = fmaxf(m, __shfl_xor(m, 4));
    m = fmaxf(m, __shfl_xor(m, 8));
    mx[r] = m;
  }
  const float SCL = 0.125f * 1.4426950408889634f;   // (1/sqrt(64)) * log2(e)
  float sm[4] = {0.f, 0.f, 0.f, 0.f};
#pragma unroll
  for (int nt = 0; nt < 16; ++nt)
#pragma unroll
    for (int r = 0; r < 4; ++r) {
      float p = exp2f((sc[nt][r] - mx[r]) * SCL);
      sc[nt][r] = p;
      sm[r] += p;
    }
#pragma unroll
  for (int r = 0; r < 4; ++r) {
    float s = sm[r];
    s += __shfl_xor(s, 1);
    s += __shfl_xor(s, 2);
    s += __shfl_xor(s, 4);
    s += __shfl_xor(s, 8);
    inv[r] = 1.0f / s;
  }
  __syncthreads();            // all waves done reading sKe
  char* pb = smem + wid * 8192;  // P aliases sKe region: [16 rows][512B] per wave
#pragma unroll
  for (int nt = 0; nt < 16; ++nt)
#pragma unroll
    for (int r = 0; r < 4; ++r) {
      int row = hi * 4 + r;
      int kk = nt * 16 + lo;
      *(u16*)(pb + row * 512 + ((kk * 2) ^ ((row & 7) << 4))) = f2bf(sc[nt][r] * inv[r]);
    }
  __syncthreads();
  s16x8 pa[8];
#pragma unroll
  for (int ks = 0; ks < 8; ++ks)
    pa[ks] = *(const s16x8*)(pb + lo * 512 + ((ks * 64 + hi * 16) ^ ((lo & 7) << 4)));
#pragma unroll
  for (int dt = 0; dt < 4; ++dt) {
    int dd = dt * 16 + lo;
    int sw = (dd & 7) << 4;
    f32x4 o = {0.f, 0.f, 0.f, 0.f};
#pragma unroll
    for (int ks = 0; ks < 8; ++ks) {
      s16x8 vb = *(const s16x8*)(sVf + dd * 512 + ((ks * 64 + hi * 16) ^ sw));
      o = __builtin_amdgcn_mfma_f32_16x16x32_bf16(pa[ks], vb, o, 0, 0, 0);
    }
#pragma unroll
    for (int r = 0; r < 4; ++r) {
      int row = n0 + wid * 16 + hi * 4 + r;
      float x = o[r];
      float g = 0.5f * x * (1.0f + erff(x * 0.7071067811865476f));
      attn[(size_t)(b * 4096 + row) * 1024 + h * 64 + dd] = f2bf(g);
    }
  }
}

// ---------- launcher ----------
extern "C" void kernel_launch(void* const* d_in, const int* in_sizes, int n_in,
                              void* d_out, int out_size, void* d_ws, size_t ws_size,
                              hipStream_t stream) {
  const float* x  = (const float*)d_in[0];
  const float* Wq = (const float*)d_in[1];
  const float* Wk = (const float*)d_in[2];
  const float* Wv = (const float*)d_in[3];
  const float* We = (const float*)d_in[4];
  const float* bE = (const float*)d_in[5];
  const float* Wf = (const float*)d_in[6];
  const float* bF = (const float*)d_in[7];
  const float* Wo = (const float*)d_in[8];
  const float* bo = (const float*)d_in[9];
  float* out = (float*)d_out;

  char* ws = (char*)d_ws;
  u16* xb   = (u16*)(ws);                 // 16,777,216 B  [8192][1024] bf16
  u16* Wqkv = (u16*)(ws + 16777216);      //  6,291,456 B  [3072][1024] bf16
  u16* Wob  = (u16*)(ws + 23068672);      //  2,097,152 B  [1024][1024] bf16
  u16* QKV  = (u16*)(ws + 25165824);      // 50,331,648 B  [8192][3072] bf16
  u16* KeT  = (u16*)(ws + 75497472);      //  1,048,576 B  [32][256][64] bf16
  u16* Vf   = (u16*)(ws + 76546048);      //  1,048,576 B  [32][64][256] bf16
  u16* attn = (u16*)(ws + 77594624);      // 16,777,216 B  [8192][1024] bf16
  float* part = (float*)(ws);             // 16,777,216 B  aliases xb (dead after QKV GEMM)

  cast_f32_bf16<<<8192, 256, 0, stream>>>(x, xb, 2097152);
  cast_f32_bf16<<<1024, 256, 0, stream>>>(Wq, Wqkv, 262144);
  cast_f32_bf16<<<1024, 256, 0, stream>>>(Wk, Wqkv + 1048576, 262144);
  cast_f32_bf16<<<1024, 256, 0, stream>>>(Wv, Wqkv + 2097152, 262144);
  cast_f32_bf16<<<1024, 256, 0, stream>>>(Wo, Wob, 262144);

  // QKV projection: [8192,3072] = x[8192,1024] @ Wqkv[3072,1024]^T
  gemm_pipe<0><<<dim3(12, 64), 256, 0, stream>>>(xb, Wqkv, QKV, nullptr,
                                                 1024, 1024, 1024, 3072);
  // Ke/Vf low-rank projections: 4-way n-split partials + reduce
  kevf_kernel<<<dim3(4, 32, 8), 256, 0, stream>>>(We, Wf, QKV, part);
  kevf_reduce<<<256, 256, 0, stream>>>(part, bE, bF, KeT, Vf);
  // fused scores/softmax/PV/gelu
  attn_fused<<<dim3(64, 32), 256, 0, stream>>>(QKV, KeT, Vf, attn);
  // output projection + bias
  gemm_pipe<1><<<dim3(4, 64), 256, 0, stream>>>(attn, Wob, out, bo,
                                                1024, 1024, 1024, 1024);
}